// Round 3
// baseline (1187.086 us; speedup 1.0000x reference)
//
#include <hip/hip_runtime.h>

#define N_ 16
#define C_ 256
#define H_ 128
#define W_ 128
#define O_ 256
#define HW_ (H_ * W_)
#define CHW_ (C_ * HW_)
#define WELEMS (O_ * C_ * 9)   // 589824

// LDS line stride 80B (40 bf16; 32 used). 80/16 = 5 coprime with the 8
// 16B bank-groups -> b128 reads/writes at consecutive-line lanes are 2-way
// max per 16-lane phase (free, m136).
#define LSTRIDE 80
#define LINES 66            // w' = 0..65 covers w0-1 .. w0+64
#define ROWS_ST 6           // input rows h0-1 .. h0+4
#define BUFB (ROWS_ST * LINES * LSTRIDE)   // 31680 B per buffer

typedef short bf16x8 __attribute__((ext_vector_type(8)));
typedef float f32x4 __attribute__((ext_vector_type(4)));

__global__ void absum_k(const float* __restrict__ w, float* __restrict__ sum) {
  int tid = blockIdx.x * blockDim.x + threadIdx.x;
  float s = 0.f;
  for (int i = tid; i < WELEMS; i += gridDim.x * blockDim.x) s += fabsf(w[i]);
  #pragma unroll
  for (int off = 32; off > 0; off >>= 1) s += __shfl_down(s, off, 64);
  if ((threadIdx.x & 63) == 0) atomicAdd(sum, s);
}

__global__ void quant_k(const float* __restrict__ w, const float* __restrict__ sum,
                        unsigned short* __restrict__ wp) {
  int i = blockIdx.x * blockDim.x + threadIdx.x;
  if (i >= WELEMS) return;
  float scale = fmaxf(sum[0] * (1.0f / (float)WELEMS), 1e-5f);
  int kk = i % 9;              // ky*3+kx
  int c = (i / 9) % C_;
  int o = i / (9 * C_);
  float q = rintf(w[i] / scale);
  q = fminf(1.f, fmaxf(-1.f, q));
  wp[(kk * O_ + o) * C_ + c] = __builtin_bit_cast(unsigned short, (__bf16)q);
}

// Block: 128 o x [4 output rows x 64 w]. 512 threads = 8 waves (2 o x 4 rows).
// Double-buffered LDS X tile: [6 rows][66 w'][32 c] bf16 per buffer.
__global__ void __launch_bounds__(512, 4)
conv_k(const float* __restrict__ x,
       const float* __restrict__ bias,
       const unsigned short* __restrict__ wp,
       const float* __restrict__ sum,
       float* __restrict__ out) {
  __shared__ __attribute__((aligned(128))) unsigned char Xs[2][BUFB];

  // chunked XCD swizzle over 2048 blocks (2048 % 8 == 0, bijective)
  const int swz = (blockIdx.x & 7) * 256 + (blockIdx.x >> 3);
  const int pid = swz >> 2, sub = swz & 3;
  const int ohalf = sub >> 1, wblk = sub & 1;
  const int spid = pid;                    // pids already contiguous per XCD
  const int n = spid >> 5;                 // 16
  const int h0 = (spid & 31) << 2;         // 32 h-blocks x 4 rows
  const int w0 = wblk << 6;
  const int o_blk = ohalf << 7;

  const int tid = threadIdx.x;
  const int wid = tid >> 6, lane = tid & 63;
  const int l15 = lane & 15, g = lane >> 4;
  const int wmo = (wid >> 2) << 6;         // wave o-offset: 0 or 64
  const int r = wid & 3;                   // wave output row 0..3

  const float* xn = x + (long)n * CHW_;

  // ---- per-thread staging coords (compile-time unrolled over it=0..2)
  // main: W = it*512+tid -> row = W>>8 (0..5), sw = W&63, cg = (W>>6)&3
  // pad (tid<48): side = tid&1, cg = (tid>>1)&3, row = tid>>3
  const int p_side = tid & 1, p_cg = (tid >> 1) & 3, p_row = tid >> 3;
  const int p_w = w0 - 1 + p_side * 65;
  const int p_h = h0 - 1 + p_row;
  const bool p_ok = (tid < 48) && ((unsigned)p_h < (unsigned)H_) &&
                    ((unsigned)p_w < (unsigned)W_);

  f32x4 acc[4][4];
  #pragma unroll
  for (int i = 0; i < 4; ++i)
    #pragma unroll
    for (int j = 0; j < 4; ++j) acc[i][j] = (f32x4){0.f, 0.f, 0.f, 0.f};

  float v[3][8];
  float vp[8];

  // ---------- helpers as lambdas ----------
  auto ldreg = [&](int c0) {
    #pragma unroll
    for (int it = 0; it < 3; ++it) {
      const int Wx = it * 512 + tid;
      const int row = Wx >> 8, sw = Wx & 63, cg = (Wx >> 6) & 3;
      const int h_in = h0 - 1 + row;
      const bool ok = (unsigned)h_in < (unsigned)H_;
      const float* s = xn + (long)(c0 + (cg << 3)) * HW_ + h_in * W_ + w0 + sw;
      #pragma unroll
      for (int k = 0; k < 8; ++k)
        v[it][k] = ok ? s[(long)k * HW_] : 0.f;
    }
    if (tid < 48) {
      const float* s = xn + (long)(c0 + (p_cg << 3)) * HW_ + p_h * W_ + p_w;
      #pragma unroll
      for (int k = 0; k < 8; ++k)
        vp[k] = p_ok ? s[(long)k * HW_] : 0.f;
    }
  };

  auto cvtwrite = [&](int b) {
    #pragma unroll
    for (int it = 0; it < 3; ++it) {
      const int Wx = it * 512 + tid;
      const int row = Wx >> 8, sw = Wx & 63, cg = (Wx >> 6) & 3;
      bf16x8 pk;
      #pragma unroll
      for (int k = 0; k < 8; ++k)
        pk[k] = (short)__builtin_bit_cast(unsigned short, (__bf16)v[it][k]);
      *(bf16x8*)(&Xs[b][(row * LINES + sw + 1) * LSTRIDE + (cg << 4)]) = pk;
    }
    if (tid < 48) {
      bf16x8 pk;
      #pragma unroll
      for (int k = 0; k < 8; ++k)
        pk[k] = (short)__builtin_bit_cast(unsigned short, (__bf16)vp[k]);
      *(bf16x8*)(&Xs[b][(p_row * LINES + p_side * 65) * LSTRIDE + (p_cg << 4)]) = pk;
    }
  };

  auto compute = [&](int b, int c0) {
    __builtin_amdgcn_s_setprio(1);
    #pragma unroll
    for (int kk = 0; kk < 9; ++kk) {
      const int ky = kk / 3, kx = kk - ky * 3;
      const int li = r + ky;
      const unsigned short* abase =
          wp + ((kk * O_ + o_blk + wmo + l15) * C_) + c0 + (g << 3);
      bf16x8 a[4];
      #pragma unroll
      for (int mi = 0; mi < 4; ++mi)
        a[mi] = *(const bf16x8*)(abase + (mi << 4) * C_);
      #pragma unroll
      for (int ni = 0; ni < 4; ++ni) {
        const int wq = (ni << 4) + l15 + kx;
        const bf16x8 bb = *(const bf16x8*)(&Xs[b][(li * LINES + wq) * LSTRIDE + (g << 4)]);
        #pragma unroll
        for (int mi = 0; mi < 4; ++mi)
          acc[mi][ni] = __builtin_amdgcn_mfma_f32_16x16x32_bf16(a[mi], bb, acc[mi][ni], 0, 0, 0);
      }
    }
    __builtin_amdgcn_s_setprio(0);
  };

  // ---------- pipelined main loop: 8 c-chunks, dbuf, 1 barrier/chunk ----------
  ldreg(0);
  cvtwrite(0);
  __syncthreads();
  #pragma unroll
  for (int t = 0; t < 8; ++t) {
    if (t < 7) ldreg((t + 1) << 5);       // issue next chunk's loads early
    compute(t & 1, t << 5);
    if (t < 7) cvtwrite((t + 1) & 1);     // write into the other buffer
    __syncthreads();
  }

  // ---- epilogue: out = scale*acc + bias. C/D: col = lane&15 (w), row = (lane>>4)*4+q (o)
  const float scale = fmaxf(sum[0] * (1.0f / (float)WELEMS), 1e-5f);
  const int h_out = h0 + r;
  #pragma unroll
  for (int mi = 0; mi < 4; ++mi) {
    #pragma unroll
    for (int q = 0; q < 4; ++q) {
      const int o = o_blk + wmo + (mi << 4) + (g << 2) + q;
      const float bv = bias[o];
      float* orow = out + ((long)n * O_ + o) * (long)HW_ + h_out * W_;
      #pragma unroll
      for (int ni = 0; ni < 4; ++ni) {
        const int wc = w0 + (ni << 4) + l15;
        orow[wc] = acc[mi][ni][q] * scale + bv;
      }
    }
  }
}

extern "C" void kernel_launch(void* const* d_in, const int* in_sizes, int n_in,
                              void* d_out, int out_size, void* d_ws, size_t ws_size,
                              hipStream_t stream) {
  const float* x = (const float*)d_in[0];
  const float* w = (const float*)d_in[1];
  const float* bias = (const float*)d_in[2];
  float* out = (float*)d_out;
  float* sum = (float*)d_ws;
  unsigned short* wp = (unsigned short*)((char*)d_ws + 16);

  hipMemsetAsync(d_ws, 0, 4, stream);
  absum_k<<<256, 256, 0, stream>>>(w, sum);
  quant_k<<<WELEMS / 256, 256, 0, stream>>>(w, sum, wp);
  conv_k<<<2048, 512, 0, stream>>>(x, bias, wp, sum, out);
}

// Round 4
// 1062.379 us; speedup vs baseline: 1.1174x; 1.1174x over previous
//
#include <hip/hip_runtime.h>

#define N_ 16
#define C_ 256
#define H_ 128
#define W_ 128
#define O_ 256
#define HW_ (H_ * W_)
#define CHW_ (C_ * HW_)
#define WELEMS (O_ * C_ * 9)   // 589824

// LDS line stride 80B (40 bf16; 32 used). 80/16 = 5 coprime with the 8
// 16B bank-groups -> b128 reads/writes at consecutive-line lanes are 2-way
// max (free, m136).
#define LSTRIDE 80
#define LINES 66            // w' = 0..65 covers w0-1 .. w0+64
#define ROWS_ST 6           // input rows h0-1 .. h0+4
#define BUFB (ROWS_ST * LINES * LSTRIDE)   // 31680 B per buffer

typedef short bf16x8 __attribute__((ext_vector_type(8)));
typedef float f32x4 __attribute__((ext_vector_type(4)));

__global__ void absum_k(const float* __restrict__ w, float* __restrict__ sum) {
  int tid = blockIdx.x * blockDim.x + threadIdx.x;
  float s = 0.f;
  for (int i = tid; i < WELEMS; i += gridDim.x * blockDim.x) s += fabsf(w[i]);
  #pragma unroll
  for (int off = 32; off > 0; off >>= 1) s += __shfl_down(s, off, 64);
  if ((threadIdx.x & 63) == 0) atomicAdd(sum, s);
}

__global__ void quant_k(const float* __restrict__ w, const float* __restrict__ sum,
                        unsigned short* __restrict__ wp) {
  int i = blockIdx.x * blockDim.x + threadIdx.x;
  if (i >= WELEMS) return;
  float scale = fmaxf(sum[0] * (1.0f / (float)WELEMS), 1e-5f);
  int kk = i % 9;              // ky*3+kx
  int c = (i / 9) % C_;
  int o = i / (9 * C_);
  float q = rintf(w[i] / scale);
  q = fminf(1.f, fmaxf(-1.f, q));
  wp[(kk * O_ + o) * C_ + c] = __builtin_bit_cast(unsigned short, (__bf16)q);
}

// Block: 128 o x [4 output rows x 64 w]. 512 threads = 8 waves (2 o x 4 rows).
// Double-buffered LDS X tile: [6 rows][66 w'][32 c] bf16 per buffer.
// Pipeline: per chunk, 3 staging batches (<=8 f32 in flight each) interleaved
// with 3-tap MFMA segments; sched_barrier(0) pins the segment order so the
// compiler cannot hoist all loads (R3's spill cause).
__global__ void __launch_bounds__(512, 4)
conv_k(const float* __restrict__ x,
       const float* __restrict__ bias,
       const unsigned short* __restrict__ wp,
       const float* __restrict__ sum,
       float* __restrict__ out) {
  __shared__ __attribute__((aligned(128))) unsigned char Xs[2][BUFB];

  // chunked XCD swizzle over 2048 blocks (2048 % 8 == 0, bijective)
  const int swz = (blockIdx.x & 7) * 256 + (blockIdx.x >> 3);
  const int pid = swz >> 2, sub = swz & 3;
  const int ohalf = sub >> 1, wblk = sub & 1;
  const int n = pid >> 5;                  // 16
  const int h0 = (pid & 31) << 2;          // 32 h-blocks x 4 rows
  const int w0 = wblk << 6;
  const int o_blk = ohalf << 7;

  const int tid = threadIdx.x;
  const int wid = tid >> 6, lane = tid & 63;
  const int l15 = lane & 15, g = lane >> 4;
  const int wmo = (wid >> 2) << 6;         // wave o-offset: 0 or 64
  const int r = wid & 3;                   // wave output row 0..3

  const float* xn = x + (long)n * CHW_;

  // pad columns w'=0,65 handled by threads 0..47
  const int p_side = tid & 1, p_cg = (tid >> 1) & 3, p_row = tid >> 3;
  const int p_w = w0 - 1 + p_side * 65;
  const int p_h = h0 - 1 + p_row;
  const bool p_in = (tid < 48);
  const bool p_ok = p_in && ((unsigned)p_h < (unsigned)H_) &&
                    ((unsigned)p_w < (unsigned)W_);

  f32x4 acc[4][4];
  #pragma unroll
  for (int i = 0; i < 4; ++i)
    #pragma unroll
    for (int j = 0; j < 4; ++j) acc[i][j] = (f32x4){0.f, 0.f, 0.f, 0.f};

  float v0[8], v1[8], v2[8], vp[8];

  // ---- staging helpers: group it in {0,1,2}: Wx = it*512+tid
  auto ld8 = [&](float* d, int it, int c0) {
    const int Wx = it * 512 + tid;
    const int row = Wx >> 8, sw = Wx & 63, cg = (Wx >> 6) & 3;
    const int h_in = h0 - 1 + row;
    const bool ok = (unsigned)h_in < (unsigned)H_;
    const float* s = xn + (long)(c0 + (cg << 3)) * HW_ + h_in * W_ + w0 + sw;
    #pragma unroll
    for (int k = 0; k < 8; ++k) d[k] = ok ? s[(long)k * HW_] : 0.f;
  };
  auto wr8 = [&](const float* d, int it, int nbi) {
    const int Wx = it * 512 + tid;
    const int row = Wx >> 8, sw = Wx & 63, cg = (Wx >> 6) & 3;
    bf16x8 pk;
    #pragma unroll
    for (int k = 0; k < 8; ++k)
      pk[k] = (short)__builtin_bit_cast(unsigned short, (__bf16)d[k]);
    *(bf16x8*)(&Xs[nbi][(row * LINES + sw + 1) * LSTRIDE + (cg << 4)]) = pk;
  };
  auto ldpad = [&](int c0) {
    if (p_in) {
      const float* s = xn + (long)(c0 + (p_cg << 3)) * HW_ + p_h * W_ + p_w;
      #pragma unroll
      for (int k = 0; k < 8; ++k) vp[k] = p_ok ? s[(long)k * HW_] : 0.f;
    }
  };
  auto wrpad = [&](int nbi) {
    if (p_in) {
      bf16x8 pk;
      #pragma unroll
      for (int k = 0; k < 8; ++k)
        pk[k] = (short)__builtin_bit_cast(unsigned short, (__bf16)vp[k]);
      *(bf16x8*)(&Xs[nbi][(p_row * LINES + p_side * 65) * LSTRIDE + (p_cg << 4)]) = pk;
    }
  };

  auto tap = [&](int cbi, int c0, int kk) {
    const int ky = kk / 3, kx = kk - ky * 3;
    const int li = r + ky;
    const unsigned short* abase =
        wp + ((kk * O_ + o_blk + wmo + l15) * C_) + c0 + (g << 3);
    bf16x8 a0 = *(const bf16x8*)(abase);
    bf16x8 a1 = *(const bf16x8*)(abase + 16 * C_);
    bf16x8 a2 = *(const bf16x8*)(abase + 32 * C_);
    bf16x8 a3 = *(const bf16x8*)(abase + 48 * C_);
    #pragma unroll
    for (int ni = 0; ni < 4; ++ni) {
      const int wq = (ni << 4) + l15 + kx;
      const bf16x8 bb = *(const bf16x8*)(&Xs[cbi][(li * LINES + wq) * LSTRIDE + (g << 4)]);
      acc[0][ni] = __builtin_amdgcn_mfma_f32_16x16x32_bf16(a0, bb, acc[0][ni], 0, 0, 0);
      acc[1][ni] = __builtin_amdgcn_mfma_f32_16x16x32_bf16(a1, bb, acc[1][ni], 0, 0, 0);
      acc[2][ni] = __builtin_amdgcn_mfma_f32_16x16x32_bf16(a2, bb, acc[2][ni], 0, 0, 0);
      acc[3][ni] = __builtin_amdgcn_mfma_f32_16x16x32_bf16(a3, bb, acc[3][ni], 0, 0, 0);
    }
  };

  // ---- prologue: stage chunk 0 into buffer 0
  ld8(v0, 0, 0); ld8(v1, 1, 0); ld8(v2, 2, 0); ldpad(0);
  wr8(v0, 0, 0); wr8(v1, 1, 0); wr8(v2, 2, 0); wrpad(0);
  __syncthreads();

  // ---- main loop: 7 pipelined chunks, 1 barrier each
  for (int t = 0; t < 7; ++t) {
    const int cbi = t & 1, nbi = cbi ^ 1;
    const int c0 = t << 5, c0n = (t + 1) << 5;

    ld8(v0, 0, c0n); ldpad(c0n);
    __builtin_amdgcn_sched_barrier(0);
    __builtin_amdgcn_s_setprio(1);
    tap(cbi, c0, 0); tap(cbi, c0, 1); tap(cbi, c0, 2);
    __builtin_amdgcn_s_setprio(0);
    __builtin_amdgcn_sched_barrier(0);
    wr8(v0, 0, nbi); wrpad(nbi);
    ld8(v1, 1, c0n);
    __builtin_amdgcn_sched_barrier(0);
    __builtin_amdgcn_s_setprio(1);
    tap(cbi, c0, 3); tap(cbi, c0, 4); tap(cbi, c0, 5);
    __builtin_amdgcn_s_setprio(0);
    __builtin_amdgcn_sched_barrier(0);
    wr8(v1, 1, nbi);
    ld8(v2, 2, c0n);
    __builtin_amdgcn_sched_barrier(0);
    __builtin_amdgcn_s_setprio(1);
    tap(cbi, c0, 6); tap(cbi, c0, 7); tap(cbi, c0, 8);
    __builtin_amdgcn_s_setprio(0);
    __builtin_amdgcn_sched_barrier(0);
    wr8(v2, 2, nbi);
    __syncthreads();
  }

  // ---- final chunk (c0 = 224, buffer 1), no staging
  __builtin_amdgcn_s_setprio(1);
  #pragma unroll
  for (int kk = 0; kk < 9; ++kk) tap(1, 224, kk);
  __builtin_amdgcn_s_setprio(0);

  // ---- epilogue: out = scale*acc + bias. C/D: col = lane&15 (w), row = (lane>>4)*4+q (o)
  const float scale = fmaxf(sum[0] * (1.0f / (float)WELEMS), 1e-5f);
  const int h_out = h0 + r;
  #pragma unroll
  for (int mi = 0; mi < 4; ++mi) {
    #pragma unroll
    for (int q = 0; q < 4; ++q) {
      const int o = o_blk + wmo + (mi << 4) + (g << 2) + q;
      const float bv = bias[o];
      float* orow = out + ((long)n * O_ + o) * (long)HW_ + h_out * W_;
      #pragma unroll
      for (int ni = 0; ni < 4; ++ni) {
        const int wc = w0 + (ni << 4) + l15;
        orow[wc] = acc[mi][ni][q] * scale + bv;
      }
    }
  }
}

extern "C" void kernel_launch(void* const* d_in, const int* in_sizes, int n_in,
                              void* d_out, int out_size, void* d_ws, size_t ws_size,
                              hipStream_t stream) {
  const float* x = (const float*)d_in[0];
  const float* w = (const float*)d_in[1];
  const float* bias = (const float*)d_in[2];
  float* out = (float*)d_out;
  float* sum = (float*)d_ws;
  unsigned short* wp = (unsigned short*)((char*)d_ws + 16);

  hipMemsetAsync(d_ws, 0, 4, stream);
  absum_k<<<256, 256, 0, stream>>>(w, sum);
  quant_k<<<WELEMS / 256, 256, 0, stream>>>(w, sum, wp);
  conv_k<<<2048, 512, 0, stream>>>(x, bias, wp, sum, out);
}

// Round 5
// 760.728 us; speedup vs baseline: 1.5605x; 1.3965x over previous
//
#include <hip/hip_runtime.h>

#define N_ 16
#define C_ 256
#define H_ 128
#define W_ 128
#define O_ 256
#define HW_ (H_ * W_)
#define CHW_ (C_ * HW_)
#define WELEMS (O_ * C_ * 9)   // 589824

// ---- padded bf16 x layout: xb[n][h' 0..129][cg 0..7][w' 0..129][32c]
// line = 64 B per (point, cg); h'=h+1, w'=w+1; halo rows/cols are zero.
// Within each 64B line the four 16B sub-chunks are stored PRE-PERMUTED:
// slot j holds c-sub (j ^ ((w'>>1)&3)) so that global_load_lds (linear) +
// swizzled ds_read gives 2-way-max bank conflicts (free).
#define XH 130
#define XW 130
#define XB_LINE 64
#define XB_BYTES ((long)N_ * XH * 8 * XW * XB_LINE)   // 138,444,800
#define XB_OFF (2l << 20)
#define WS_NEED (XB_OFF + XB_BYTES)

#define ROWB 4224            // 66 points * 64 B per staged row
#define BUFB (6 * ROWB)      // 25344 B per buffer

typedef short bf16x8 __attribute__((ext_vector_type(8)));
typedef float f32x4 __attribute__((ext_vector_type(4)));

#define GLOAD_LDS16(g, l)                                                     \
  __builtin_amdgcn_global_load_lds(                                           \
      (const __attribute__((address_space(1))) unsigned int*)(g),             \
      (__attribute__((address_space(3))) unsigned int*)(l), 16, 0, 0)

__global__ void absum_k(const float* __restrict__ w, float* __restrict__ sum) {
  int tid = blockIdx.x * blockDim.x + threadIdx.x;
  float s = 0.f;
  for (int i = tid; i < WELEMS; i += gridDim.x * blockDim.x) s += fabsf(w[i]);
  #pragma unroll
  for (int off = 32; off > 0; off >>= 1) s += __shfl_down(s, off, 64);
  if ((threadIdx.x & 63) == 0) atomicAdd(sum, s);
}

__global__ void quant_k(const float* __restrict__ w, const float* __restrict__ sum,
                        unsigned short* __restrict__ wp) {
  int i = blockIdx.x * blockDim.x + threadIdx.x;
  if (i >= WELEMS) return;
  float scale = fmaxf(sum[0] * (1.0f / (float)WELEMS), 1e-5f);
  int kk = i % 9;              // ky*3+kx
  int c = (i / 9) % C_;
  int o = i / (9 * C_);
  float q = rintf(w[i] / scale);
  q = fminf(1.f, fmaxf(-1.f, q));
  wp[(kk * O_ + o) * C_ + c] = __builtin_bit_cast(unsigned short, (__bf16)q);
}

// zero the halo lines of xb (h'=0,129 all w'; w'=0,129 all h')
__global__ void halo_k(unsigned char* __restrict__ xbb) {
  int i = blockIdx.x * 256 + threadIdx.x;
  if (i >= 66560) return;
  long line;
  if (i < 33280) {           // h-halo: ((n*2+hh)*8+cg)*130 + wq
    int wq = i % 130; int t = i / 130;
    int cg = t & 7; t >>= 3;
    int hh = t & 1; int nn = t >> 1;
    line = (((long)nn * XH + hh * 129) * 8 + cg) * XW + wq;
  } else {                   // w-halo: (((n*130+h')*8+cg)*2 + side
    int j = i - 33280;
    int side = j & 1; int t = j >> 1;
    int cg = t & 7; t >>= 3;
    int hp = t % 130; int nn = t / 130;
    line = (((long)nn * XH + hp) * 8 + cg) * XW + side * 129;
  }
  f32x4 z = (f32x4){0.f, 0.f, 0.f, 0.f};
  #pragma unroll
  for (int j4 = 0; j4 < 4; ++j4)
    *(f32x4*)(xbb + line * XB_LINE + j4 * 16) = z;
}

// x NCHW f32 -> xb (layout above). Block: (n, h, 64-w half); 256 threads.
// Reads coalesced (64 consecutive w per instr); each 64B dest line written
// entirely by one thread.
__global__ void xform_k(const float* __restrict__ x, unsigned char* __restrict__ xbb) {
  const int b = blockIdx.x;
  const int wh = b & 1, h = (b >> 1) & 127, n = b >> 8;
  const int t = threadIdx.x;
  const int wl = t & 63, q = t >> 6;                 // q = 64c quarter
  const int w = (wh << 6) + wl;
  const float* s0 = x + ((long)n * C_ + q * 64) * HW_ + h * W_ + w;
  const int mw = ((w + 1) >> 1) & 3;
  const long lbase = (((long)n * XH + (h + 1)) * 8) * XW + (w + 1);
  #pragma unroll
  for (int sub = 0; sub < 4; ++sub) {
    float v[16];
    #pragma unroll
    for (int k = 0; k < 16; ++k) v[k] = s0[(long)(sub * 16 + k) * HW_];
    bf16x8 p0, p1;
    #pragma unroll
    for (int k = 0; k < 8; ++k) {
      p0[k] = (short)__builtin_bit_cast(unsigned short, (__bf16)v[k]);
      p1[k] = (short)__builtin_bit_cast(unsigned short, (__bf16)v[8 + k]);
    }
    const int cg = q * 2 + (sub >> 1);
    const int j0 = (sub & 1) * 2;
    unsigned char* lp = xbb + (lbase + (long)cg * XW) * XB_LINE;
    *(bf16x8*)(lp + ((j0) ^ mw) * 16) = p0;
    *(bf16x8*)(lp + ((j0 + 1) ^ mw) * 16) = p1;
  }
}

// ---- fast conv: 128 o x [4 rows x 64 w] per block, 512 thr (8 waves: 2 o x 4 rows).
// Staging = global_load_lds dwordx4 from xb (contiguous 4224 B per row-chunk),
// double-buffered, issued between taps 1 and 2; one barrier per chunk.
__global__ void __launch_bounds__(512, 4)
conv_k(const unsigned char* __restrict__ xbb,
       const float* __restrict__ bias,
       const unsigned short* __restrict__ wp,
       const float* __restrict__ sum,
       float* __restrict__ out) {
  __shared__ __attribute__((aligned(128))) unsigned char Xs[2][BUFB];

  // chunked XCD swizzle over 2048 blocks (2048 % 8 == 0, bijective)
  const int swz = (blockIdx.x & 7) * 256 + (blockIdx.x >> 3);
  const int pid = swz >> 2, sub = swz & 3;
  const int ohalf = sub >> 1, wblk = sub & 1;
  const int n = pid >> 5;
  const int h0 = (pid & 31) << 2;
  const int w0 = wblk << 6;
  const int o_blk = ohalf << 7;

  const int tid = threadIdx.x;
  const int wid = tid >> 6, lane = tid & 63;
  const int l15 = lane & 15, g = lane >> 4;
  const int wmo = (wid >> 2) << 6;         // wave o-offset: 0 or 64
  const int r = wid & 3;                   // wave output row 0..3

  f32x4 acc[4][4];
  #pragma unroll
  for (int i = 0; i < 4; ++i)
    #pragma unroll
    for (int j = 0; j < 4; ++j) acc[i][j] = (f32x4){0.f, 0.f, 0.f, 0.f};

  // waves 0..5 each stage one input row (66 points x 64B = 264 x 16B chunks)
  auto stage = [&](int b, int cg) {
    if (wid < 6) {
      const unsigned char* src =
          xbb + ((((long)n * XH + h0 + wid) * 8 + cg) * XW + w0) * XB_LINE;
      unsigned char* dst = &Xs[b][wid * ROWB];
      #pragma unroll
      for (int it = 0; it < 4; ++it)
        GLOAD_LDS16(src + (it * 64 + lane) * 16, dst + it * 1024);
      if (lane < 8)
        GLOAD_LDS16(src + (256 + lane) * 16, dst + 4096);
    }
  };

  auto tap = [&](int cbi, int c0, int kk) {
    const int ky = kk / 3, kx = kk - ky * 3;
    const int li = r + ky;
    const unsigned short* abase =
        wp + ((kk * O_ + o_blk + wmo + l15) * C_) + c0 + (g << 3);
    bf16x8 a0 = *(const bf16x8*)(abase);
    bf16x8 a1 = *(const bf16x8*)(abase + 16 * C_);
    bf16x8 a2 = *(const bf16x8*)(abase + 32 * C_);
    bf16x8 a3 = *(const bf16x8*)(abase + 48 * C_);
    #pragma unroll
    for (int ni = 0; ni < 4; ++ni) {
      const int wq = (ni << 4) + l15 + kx;            // staged line index 0..65
      const int s = g ^ ((wq >> 1) & 3);              // read-side swizzle
      const bf16x8 bb = *(const bf16x8*)(&Xs[cbi][li * ROWB + wq * 64 + s * 16]);
      acc[0][ni] = __builtin_amdgcn_mfma_f32_16x16x32_bf16(a0, bb, acc[0][ni], 0, 0, 0);
      acc[1][ni] = __builtin_amdgcn_mfma_f32_16x16x32_bf16(a1, bb, acc[1][ni], 0, 0, 0);
      acc[2][ni] = __builtin_amdgcn_mfma_f32_16x16x32_bf16(a2, bb, acc[2][ni], 0, 0, 0);
      acc[3][ni] = __builtin_amdgcn_mfma_f32_16x16x32_bf16(a3, bb, acc[3][ni], 0, 0, 0);
    }
  };

  stage(0, 0);
  __syncthreads();

  for (int t = 0; t < 8; ++t) {
    const int cbi = t & 1;
    const int c0 = t << 5;
    __builtin_amdgcn_s_setprio(1);
    tap(cbi, c0, 0); tap(cbi, c0, 1);
    __builtin_amdgcn_s_setprio(0);
    if (t < 7) {
      __builtin_amdgcn_sched_barrier(0);
      stage(cbi ^ 1, t + 1);
      __builtin_amdgcn_sched_barrier(0);
    }
    __builtin_amdgcn_s_setprio(1);
    tap(cbi, c0, 2); tap(cbi, c0, 3); tap(cbi, c0, 4);
    tap(cbi, c0, 5); tap(cbi, c0, 6); tap(cbi, c0, 8 - 1); tap(cbi, c0, 8);
    __builtin_amdgcn_s_setprio(0);
    __syncthreads();
  }

  // epilogue: out = scale*acc + bias. C/D: col = lane&15 (w), row = (lane>>4)*4+q (o)
  const float scale = fmaxf(sum[0] * (1.0f / (float)WELEMS), 1e-5f);
  const int h_out = h0 + r;
  #pragma unroll
  for (int mi = 0; mi < 4; ++mi) {
    #pragma unroll
    for (int q = 0; q < 4; ++q) {
      const int o = o_blk + wmo + (mi << 4) + (g << 2) + q;
      const float bv = bias[o];
      float* orow = out + ((long)n * O_ + o) * (long)HW_ + h_out * W_;
      #pragma unroll
      for (int ni = 0; ni < 4; ++ni) {
        const int wc = w0 + (ni << 4) + l15;
        orow[wc] = acc[mi][ni][q] * scale + bv;
      }
    }
  }
}

// ================= fallback (R2 kernel, used only if ws too small) =========
#define LSTRIDE 80
#define LINES_FB 130
__global__ void __launch_bounds__(512, 4)
conv_fb(const float* __restrict__ x,
        const float* __restrict__ bias,
        const unsigned short* __restrict__ wp,
        const float* __restrict__ sum,
        float* __restrict__ out) {
  __shared__ __attribute__((aligned(128))) unsigned char Xs[4 * 130 * LSTRIDE];
  const int bid = blockIdx.x;
  const int pid = bid >> 1, ohalf = bid & 1;
  const int spid = (pid & 7) * 128 + (pid >> 3);
  const int n = spid >> 6;
  const int h0 = (spid & 63) << 1;
  const int o_blk = ohalf << 7;
  const int tid = threadIdx.x;
  if (tid < 128) {
    const int li = tid >> 5, sel = (tid >> 4) & 1, word = tid & 15;
    const int wq = sel ? 129 : 0;
    *(int*)(Xs + (li * LINES_FB + wq) * LSTRIDE + word * 4) = 0;
  }
  const int wid = tid >> 6, lane = tid & 63;
  const int l15 = lane & 15, g = lane >> 4;
  const int wmo = (wid >> 2) << 6;
  const int wsid = wid & 3, r = wsid >> 1, wbase = (wsid & 1) << 6;
  const int sw = tid & 127, sli = tid >> 7;
  const int h_in = h0 - 1 + sli;
  const bool inb = (unsigned)h_in < (unsigned)H_;
  const float* xsrc = x + (long)n * CHW_ + (long)h_in * W_ + sw;
  unsigned char* sdst = Xs + (sli * LINES_FB + sw + 1) * LSTRIDE;
  f32x4 acc[4][4];
  #pragma unroll
  for (int i = 0; i < 4; ++i)
    #pragma unroll
    for (int j = 0; j < 4; ++j) acc[i][j] = (f32x4){0.f, 0.f, 0.f, 0.f};
  for (int c0 = 0; c0 < C_; c0 += 32) {
    #pragma unroll
    for (int cg = 0; cg < 4; ++cg) {
      bf16x8 pk = (bf16x8){0, 0, 0, 0, 0, 0, 0, 0};
      if (inb) {
        const float* s = xsrc + (long)(c0 + (cg << 3)) * HW_;
        #pragma unroll
        for (int k = 0; k < 8; ++k)
          pk[k] = (short)__builtin_bit_cast(unsigned short, (__bf16)s[(long)k * HW_]);
      }
      *(bf16x8*)(sdst + (cg << 4)) = pk;
    }
    __syncthreads();
    #pragma unroll
    for (int kk = 0; kk < 9; ++kk) {
      const int ky = kk / 3, kx = kk - ky * 3;
      const int li = r + ky;
      const unsigned short* abase =
          wp + ((kk * O_ + o_blk + wmo + l15) * C_) + c0 + (g << 3);
      bf16x8 a[4];
      #pragma unroll
      for (int mi = 0; mi < 4; ++mi)
        a[mi] = *(const bf16x8*)(abase + (mi << 4) * C_);
      #pragma unroll
      for (int ni = 0; ni < 4; ++ni) {
        const int wq = wbase + (ni << 4) + l15 + kx;
        const bf16x8 bb = *(const bf16x8*)(&Xs[(li * LINES_FB + wq) * LSTRIDE + (g << 4)]);
        #pragma unroll
        for (int mi = 0; mi < 4; ++mi)
          acc[mi][ni] = __builtin_amdgcn_mfma_f32_16x16x32_bf16(a[mi], bb, acc[mi][ni], 0, 0, 0);
      }
    }
    __syncthreads();
  }
  const float scale = fmaxf(sum[0] * (1.0f / (float)WELEMS), 1e-5f);
  const int h_out = h0 + r;
  #pragma unroll
  for (int mi = 0; mi < 4; ++mi) {
    #pragma unroll
    for (int q = 0; q < 4; ++q) {
      const int o = o_blk + wmo + (mi << 4) + (g << 2) + q;
      const float bv = bias[o];
      float* orow = out + ((long)n * O_ + o) * (long)HW_ + h_out * W_;
      #pragma unroll
      for (int ni = 0; ni < 4; ++ni) {
        const int wc = wbase + (ni << 4) + l15;
        orow[wc] = acc[mi][ni][q] * scale + bv;
      }
    }
  }
}

extern "C" void kernel_launch(void* const* d_in, const int* in_sizes, int n_in,
                              void* d_out, int out_size, void* d_ws, size_t ws_size,
                              hipStream_t stream) {
  const float* x = (const float*)d_in[0];
  const float* w = (const float*)d_in[1];
  const float* bias = (const float*)d_in[2];
  float* out = (float*)d_out;
  float* sum = (float*)d_ws;
  unsigned short* wp = (unsigned short*)((char*)d_ws + 64);

  hipMemsetAsync(d_ws, 0, 4, stream);
  absum_k<<<256, 256, 0, stream>>>(w, sum);
  quant_k<<<WELEMS / 256, 256, 0, stream>>>(w, sum, wp);

  if (ws_size >= (size_t)WS_NEED) {
    unsigned char* xbb = (unsigned char*)d_ws + XB_OFF;
    halo_k<<<260, 256, 0, stream>>>(xbb);
    xform_k<<<4096, 256, 0, stream>>>(x, xbb);
    conv_k<<<2048, 512, 0, stream>>>(xbb, bias, wp, sum, out);
  } else {
    conv_fb<<<2048, 512, 0, stream>>>(x, bias, wp, sum, out);
  }
}